// Round 1
// baseline (109.249 us; speedup 1.0000x reference)
//
#include <hip/hip_runtime.h>

#define B_DIM 4096
#define T_DIM 16384
#define WAVES_PER_BLOCK 4
#define CHUNK 256   // samples per wave per iteration (64 lanes * 4)

struct M2 { float a, b, c, d; };  // [[a,b],[c,d]]

__device__ inline M2 m2mul(const M2& X, const M2& Y) {
    M2 r;
    r.a = fmaf(X.a, Y.a, X.b * Y.c);
    r.b = fmaf(X.a, Y.b, X.b * Y.d);
    r.c = fmaf(X.c, Y.a, X.d * Y.c);
    r.d = fmaf(X.c, Y.b, X.d * Y.d);
    return r;
}

__global__ __launch_bounds__(256) void biquad_scan_kernel(
    const float* __restrict__ x, const float* __restrict__ v0in,
    const float* __restrict__ pb0, const float* __restrict__ pb1,
    const float* __restrict__ pb2, const float* __restrict__ pa1,
    const float* __restrict__ pa2,
    float* __restrict__ y, float* __restrict__ vout)
{
    const int lane = threadIdx.x & 63;
    const int wave = threadIdx.x >> 6;
    const int row  = blockIdx.x * WAVES_PER_BLOCK + wave;
    if (row >= B_DIM) return;

    const float b0 = *pb0, b1 = *pb1, b2 = *pb2, a1 = *pa1, a2 = *pa2;
    const float c0 = b1 - a1 * b0;   // state-update input coeffs
    const float c1 = b2 - a2 * b0;

    // A = [[-a1, 1], [-a2, 0]]
    M2 A  { -a1, 1.0f, -a2, 0.0f };
    M2 A2 = m2mul(A, A);
    M2 A4 = m2mul(A2, A2);

    // S[s] = A^(4*2^s) (uniform scan matrices), Q = A^(4*lane) (per-lane),
    // R = A^256 (uniform carry matrix). Repeated squaring, fully unrolled.
    M2 S0, S1, S2, S3, S4, S5;
    M2 Q { 1.f, 0.f, 0.f, 1.f };
    M2 M = A4;
    S0 = M; if (lane & 1)  Q = m2mul(M, Q); M = m2mul(M, M);
    S1 = M; if (lane & 2)  Q = m2mul(M, Q); M = m2mul(M, M);
    S2 = M; if (lane & 4)  Q = m2mul(M, Q); M = m2mul(M, M);
    S3 = M; if (lane & 8)  Q = m2mul(M, Q); M = m2mul(M, M);
    S4 = M; if (lane & 16) Q = m2mul(M, Q); M = m2mul(M, M);
    S5 = M; if (lane & 32) Q = m2mul(M, Q); M = m2mul(M, M);
    const M2 R = M;  // A^256

    const float*  xr = x + (size_t)row * T_DIM;
    float*        yr = y + (size_t)row * T_DIM;

    float vc0 = v0in[row * 2 + 0];
    float vc1 = v0in[row * 2 + 1];

    const int NIT = T_DIM / CHUNK;  // 64

    // depth-2 prefetch
    float4 xv = ((const float4*)(xr))[lane];
    float4 xn = ((const float4*)(xr + CHUNK))[lane];

    for (int i = 0; i < NIT; ++i) {
        float4 xn2 = make_float4(0.f, 0.f, 0.f, 0.f);
        if (i + 2 < NIT) xn2 = ((const float4*)(xr + (size_t)(i + 2) * CHUNK))[lane];

        // ---- build per-lane zero-start contribution d over its 4 samples ----
        float d0 = c0 * xv.x;
        float d1 = c1 * xv.x;
        {   float t0 = fmaf(c0, xv.y, fmaf(-a1, d0, d1));
            float t1 = fmaf(-a2, d0, c1 * xv.y);
            d0 = t0; d1 = t1; }
        {   float t0 = fmaf(c0, xv.z, fmaf(-a1, d0, d1));
            float t1 = fmaf(-a2, d0, c1 * xv.z);
            d0 = t0; d1 = t1; }
        {   float t0 = fmaf(c0, xv.w, fmaf(-a1, d0, d1));
            float t1 = fmaf(-a2, d0, c1 * xv.w);
            d0 = t0; d1 = t1; }

        // ---- inclusive Hillis-Steele scan over lanes: d[l] = S_s * d[l-o] + d[l] ----
        #define SCAN_STEP(Sm, o)                                        \
        {   float p0 = __shfl_up(d0, (unsigned)(o));                    \
            float p1 = __shfl_up(d1, (unsigned)(o));                    \
            if (lane < (o)) { p0 = 0.f; p1 = 0.f; }                     \
            float t0 = fmaf(Sm.a, p0, fmaf(Sm.b, p1, d0));              \
            float t1 = fmaf(Sm.c, p0, fmaf(Sm.d, p1, d1));              \
            d0 = t0; d1 = t1; }
        SCAN_STEP(S0, 1)
        SCAN_STEP(S1, 2)
        SCAN_STEP(S2, 4)
        SCAN_STEP(S3, 8)
        SCAN_STEP(S4, 16)
        SCAN_STEP(S5, 32)
        #undef SCAN_STEP

        // ---- exclusive shift ----
        float e0 = __shfl_up(d0, 1u);
        float e1 = __shfl_up(d1, 1u);
        if (lane == 0) { e0 = 0.f; e1 = 0.f; }

        // ---- per-lane start state: v_begin = A^(4*lane) * v_carry + e ----
        float v0r = fmaf(Q.a, vc0, fmaf(Q.b, vc1, e0));
        float v1r = fmaf(Q.c, vc0, fmaf(Q.d, vc1, e1));

        // ---- replay 4 samples, emit y ----
        float4 yv;
        {   float xs = xv.x; float yy = fmaf(xs, b0, v0r);
            float n0 = fmaf(-a1, yy, fmaf(xs, b1, v1r));
            float n1 = fmaf(-a2, yy, xs * b2);
            v0r = n0; v1r = n1; yv.x = yy; }
        {   float xs = xv.y; float yy = fmaf(xs, b0, v0r);
            float n0 = fmaf(-a1, yy, fmaf(xs, b1, v1r));
            float n1 = fmaf(-a2, yy, xs * b2);
            v0r = n0; v1r = n1; yv.y = yy; }
        {   float xs = xv.z; float yy = fmaf(xs, b0, v0r);
            float n0 = fmaf(-a1, yy, fmaf(xs, b1, v1r));
            float n1 = fmaf(-a2, yy, xs * b2);
            v0r = n0; v1r = n1; yv.z = yy; }
        {   float xs = xv.w; float yy = fmaf(xs, b0, v0r);
            float n0 = fmaf(-a1, yy, fmaf(xs, b1, v1r));
            float n1 = fmaf(-a2, yy, xs * b2);
            v0r = n0; v1r = n1; yv.w = yy; }

        ((float4*)(yr + (size_t)i * CHUNK))[lane] = yv;

        // ---- carry update: v_carry = A^256 * v_carry + d_scan[63] ----
        float t0 = __shfl(d0, 63);
        float t1 = __shfl(d1, 63);
        float nv0 = fmaf(R.a, vc0, fmaf(R.b, vc1, t0));
        float nv1 = fmaf(R.c, vc0, fmaf(R.d, vc1, t1));
        vc0 = nv0; vc1 = nv1;

        xv = xn; xn = xn2;
    }

    if (lane == 0) {
        vout[row * 2 + 0] = vc0;
        vout[row * 2 + 1] = vc1;
    }
}

extern "C" void kernel_launch(void* const* d_in, const int* in_sizes, int n_in,
                              void* d_out, int out_size, void* d_ws, size_t ws_size,
                              hipStream_t stream) {
    const float* x   = (const float*)d_in[0];
    const float* v0  = (const float*)d_in[1];
    const float* b0  = (const float*)d_in[2];
    const float* b1  = (const float*)d_in[3];
    const float* b2  = (const float*)d_in[4];
    const float* a1  = (const float*)d_in[5];
    const float* a2  = (const float*)d_in[6];

    float* y    = (float*)d_out;
    float* vout = (float*)d_out + (size_t)B_DIM * T_DIM;

    dim3 grid(B_DIM / WAVES_PER_BLOCK);
    dim3 block(64 * WAVES_PER_BLOCK);
    biquad_scan_kernel<<<grid, block, 0, stream>>>(x, v0, b0, b1, b2, a1, a2, y, vout);
}